// Round 11
// baseline (136.254 us; speedup 1.0000x reference)
//
#include <hip/hip_runtime.h>
#include <hip/hip_bf16.h>

typedef float f32x4 __attribute__((ext_vector_type(4)));
typedef short s16x8 __attribute__((ext_vector_type(8)));
typedef unsigned long long ull;

#define NROWS 8192
#define MCOLS 8192
#define DIM   128
#define JSPLIT 8
#define JCHUNK 1024  // cols per block
#define KVB    64    // cols per iteration
#define ITERS  16    // JCHUNK / KVB

typedef __attribute__((address_space(3))) unsigned int lds_u32;
typedef __attribute__((address_space(1))) unsigned int g_u32;

__device__ __forceinline__ void gl_lds16(const void* g, void* l) {
    __builtin_amdgcn_global_load_lds((const g_u32*)g, (lds_u32*)l, 16, 0, 0);
}

// ---- prep: row-norm bf16 Q/K + Vt transpose (adj pack now fused in flash) ----
__global__ __launch_bounds__(256) void prep11(const float* __restrict__ xi,
                                              const float* __restrict__ xj,
                                              const float* __restrict__ beta,
                                              __hip_bfloat16* __restrict__ Qbf,
                                              __hip_bfloat16* __restrict__ Kbf,
                                              __hip_bfloat16* __restrict__ Vt) {
    __shared__ float tile[64][65];
    const int tid  = threadIdx.x;
    const int w    = tid >> 6;
    const int lane = tid & 63;

    // 8 norm rows per block (2 per wave)
    {
        float b = beta[0];
#pragma unroll
        for (int sub = 0; sub < 2; ++sub) {
            int gr = blockIdx.x * 8 + w * 2 + sub;   // 0..16383
            const float* src;
            __hip_bfloat16* dst;
            int row;
            if (gr < NROWS) { row = gr;          src = xi; dst = Qbf; }
            else            { row = gr - NROWS;  src = xj; dst = Kbf; }
            const float* xr = src + (size_t)row * DIM;
            float x0 = xr[lane], x1 = xr[lane + 64];
            float ss = x0 * x0 + x1 * x1;
#pragma unroll
            for (int off = 32; off >= 1; off >>= 1) ss += __shfl_xor(ss, off);
            float s = 1.0f / sqrtf(ss);
            if (gr < NROWS) s *= b;
            __hip_bfloat16* o = dst + (size_t)row * DIM;
            o[lane]      = __float2bfloat16(x0 * s);
            o[lane + 64] = __float2bfloat16(x1 * s);
        }
    }

    // Vt transpose (raw xj), one 64x64 tile for blocks < 256
    if (blockIdx.x < 256) {
        int j0 = (blockIdx.x & 127) * 64;
        int d0 = (blockIdx.x >> 7) * 64;
#pragma unroll
        for (int c = 0; c < 16; ++c) {
            int idx = tid + 256 * c;
            int jr = idx >> 6, dc = idx & 63;
            tile[jr][dc] = xj[(size_t)(j0 + jr) * DIM + d0 + dc];
        }
        __syncthreads();
#pragma unroll
        for (int c = 0; c < 16; ++c) {
            int idx = tid + 256 * c;
            int dr = idx >> 6, jc = idx & 63;
            Vt[(size_t)(d0 + dr) * MCOLS + j0 + jc] = __float2bfloat16(tile[jc][dr]);
        }
    }
}

// ---- flash11: flash10 + fused adj stream.
//      Per iter: issue adj(t+1) dwords (oldest in vmcnt FIFO, nontemporal) ->
//      STAGE(t+1 -> other LDS buf) -> compute(t) from LDS -> ballot-pack
//      adj(t+1) to mask regs (vmcnt wait leaves stage in flight) -> barrier.
//      rt-staggered col order decorrelates the 32KB-strided adj reads
//      grid-wide (channel balance). Plain-sum softmax (|score|<=beta<1). ----
__global__ __launch_bounds__(256, 2) void flash11(const __hip_bfloat16* __restrict__ Qbf,
                                                  const __hip_bfloat16* __restrict__ Kbf,
                                                  const __hip_bfloat16* __restrict__ Vt,
                                                  const int* __restrict__ adj,
                                                  float* __restrict__ Opart,
                                                  float* __restrict__ Lpart) {
    // LDS: K[2][64][128]bf16 (2x16K) | V[2][128][64]bf16 @32768 (2x16K)
    //      P: 4 waves x 2 tiles x [16][64] swizzled @65536 (16K). Total 80K.
    __shared__ char smem[81920];

    const int tid  = threadIdx.x;
    const int w    = tid >> 6;
    const int lane = tid & 63;
    const int g    = lane >> 4;
    const int ln   = lane & 15;
    const int bid  = blockIdx.x;
    const int jc   = bid & (JSPLIT - 1);
    const int rt   = bid >> 3;            // 0..63
    const int wra  = rt * 128 + w * 32;   // wave's first row (2 tiles of 16)
    const int jbase = jc * JCHUNK;
    const int lx   = ln & 7;
    const int itoff = rt & 15;            // per-block col-order stagger

    s16x8 qf[2][4];
#pragma unroll
    for (int ti = 0; ti < 2; ++ti)
#pragma unroll
        for (int kt = 0; kt < 4; ++kt)
            qf[ti][kt] = *(const s16x8*)(Qbf + (size_t)(wra + ti * 16 + ln) * DIM + kt * 32 + g * 8);

    f32x4 zero = {0.f, 0.f, 0.f, 0.f};
    f32x4 acc[2][8];
#pragma unroll
    for (int ti = 0; ti < 2; ++ti)
#pragma unroll
        for (int dt = 0; dt < 8; ++dt) acc[ti][dt] = zero;
    float lr[2][4] = {{0.f, 0.f, 0.f, 0.f}, {0.f, 0.f, 0.f, 0.f}};

    char* pw = smem + 65536 + w * 4096;
    const int* arow = adj + (size_t)wra * MCOLS + lane;   // +u*MCOLS rows

    auto STAGE = [&](int jt, int b) {
        char* kb = smem + b * 16384;
        char* vb = smem + 32768 + b * 16384;
#pragma unroll
        for (int p = 0; p < 4; ++p) {
            int S = p * 256 + tid;
            int row = S >> 4, u = S & 15;
            gl_lds16((const char*)Kbf + (((size_t)(jt + row)) << 8) + ((u ^ (row & 7)) << 4),
                     kb + p * 4096 + w * 1024);
        }
#pragma unroll
        for (int p = 0; p < 4; ++p) {
            int S = p * 256 + tid;
            int row = S >> 3, u = S & 7;
            gl_lds16((const char*)Vt + (((size_t)row) << 14) + (((size_t)jt) << 1) + ((u ^ (row & 7)) << 4),
                     vb + p * 4096 + w * 1024);
        }
    };

    // ---- prologue: stage + adj for first tile ----
    int av[32];
    {
        const int jt0 = jbase + itoff * KVB;
        STAGE(jt0, 0);
#pragma unroll
        for (int u = 0; u < 32; ++u)
            av[u] = __builtin_nontemporal_load(arow + (size_t)u * MCOLS + jt0);
    }
    __syncthreads();
    ull mw[2][4];
#pragma unroll
    for (int ti = 0; ti < 2; ++ti)
#pragma unroll
        for (int r = 0; r < 4; ++r) mw[ti][r] = 0;
#pragma unroll
    for (int u = 0; u < 32; ++u) {
        ull b = __ballot(av[u] != 0);
        mw[u >> 4][u & 3] = (((u & 15) >> 2) == g) ? b : mw[u >> 4][u & 3];
    }

    int cur = 0;
    for (int it = 0; it < ITERS; ++it) {
        const int jt  = jbase + ((it + itoff) & (ITERS - 1)) * KVB;
        const int jtn = jbase + ((it + 1 + itoff) & (ITERS - 1)) * KVB;

        // adj loads for t+1 (oldest in FIFO; consumed at iter end)
#pragma unroll
        for (int u = 0; u < 32; ++u)
            av[u] = __builtin_nontemporal_load(arow + (size_t)u * MCOLS + jtn);
        __builtin_amdgcn_sched_barrier(0);

        // stage t+1 into the other buffer
        STAGE(jtn, cur ^ 1);
        __builtin_amdgcn_sched_barrier(0);

        const char* kb = smem + cur * 16384;
        const char* vb = smem + 32768 + cur * 16384;

        // QK: each kf fragment feeds both row tiles
        f32x4 s4[2][4];
#pragma unroll
        for (int ti = 0; ti < 2; ++ti)
#pragma unroll
            for (int ct = 0; ct < 4; ++ct) s4[ti][ct] = zero;
#pragma unroll
        for (int ct = 0; ct < 4; ++ct)
#pragma unroll
            for (int kt = 0; kt < 4; ++kt) {
                s16x8 kf = *(const s16x8*)(kb + (ct * 16 + ln) * 256 + (((kt * 4 + g) ^ lx) << 4));
                s4[0][ct] = __builtin_amdgcn_mfma_f32_16x16x32_bf16(qf[0][kt], kf, s4[0][ct], 0, 0, 0);
                s4[1][ct] = __builtin_amdgcn_mfma_f32_16x16x32_bf16(qf[1][kt], kf, s4[1][ct], 0, 0, 0);
            }

        // softmax-lite: p = adj ? exp(s) : 0; P -> swizzled LDS
#pragma unroll
        for (int ti = 0; ti < 2; ++ti)
#pragma unroll
            for (int r = 0; r < 4; ++r) {
                const int row = g * 4 + r;
                const int rs = row & 7;
#pragma unroll
                for (int ct = 0; ct < 4; ++ct) {
                    float p = ((mw[ti][r] >> (ct * 16 + ln)) & 1) ? __expf(s4[ti][ct][r]) : 0.f;
                    lr[ti][r] += p;
                    *(__hip_bfloat16*)(pw + ti * 2048 + row * 128 +
                                       (((ct * 2 + (ln >> 3)) ^ rs) << 4) + (ln & 7) * 2)
                        = __float2bfloat16(p);
                }
            }

        // PV: each vf fragment feeds both row tiles (same-wave LDS RAW on P)
#pragma unroll
        for (int kt2 = 0; kt2 < 2; ++kt2) {
            const int uo = ((kt2 * 4 + g) ^ lx) << 4;
            s16x8 pf0 = *(const s16x8*)(pw + ln * 128 + uo);
            s16x8 pf1 = *(const s16x8*)(pw + 2048 + ln * 128 + uo);
#pragma unroll
            for (int dt = 0; dt < 8; ++dt) {
                s16x8 vf = *(const s16x8*)(vb + (dt * 16 + ln) * 128 + uo);
                acc[0][dt] = __builtin_amdgcn_mfma_f32_16x16x32_bf16(pf0, vf, acc[0][dt], 0, 0, 0);
                acc[1][dt] = __builtin_amdgcn_mfma_f32_16x16x32_bf16(pf1, vf, acc[1][dt], 0, 0, 0);
            }
        }

        // ballot-pack adj(t+1): vmcnt wait drains adj (oldest), stage stays in flight
#pragma unroll
        for (int ti = 0; ti < 2; ++ti)
#pragma unroll
            for (int r = 0; r < 4; ++r) mw[ti][r] = 0;
#pragma unroll
        for (int u = 0; u < 32; ++u) {
            ull b = __ballot(av[u] != 0);
            mw[u >> 4][u & 3] = (((u & 15) >> 2) == g) ? b : mw[u >> 4][u & 3];
        }

        __syncthreads();   // drains STAGE(t+1) (overlapped by whole compute phase)
        cur ^= 1;
    }

    // row sums within 16-lane group
#pragma unroll
    for (int ti = 0; ti < 2; ++ti)
#pragma unroll
        for (int r = 0; r < 4; ++r) {
            lr[ti][r] += __shfl_xor(lr[ti][r], 1);
            lr[ti][r] += __shfl_xor(lr[ti][r], 2);
            lr[ti][r] += __shfl_xor(lr[ti][r], 4);
            lr[ti][r] += __shfl_xor(lr[ti][r], 8);
        }

    // write partials
#pragma unroll
    for (int ti = 0; ti < 2; ++ti) {
        float* ob = Opart + ((size_t)jc * NROWS + wra + ti * 16 + g * 4) * DIM;
#pragma unroll
        for (int r = 0; r < 4; ++r)
#pragma unroll
            for (int dt = 0; dt < 8; ++dt)
                ob[(size_t)r * DIM + dt * 16 + ln] = acc[ti][dt][r];
        if (ln == 0) {
#pragma unroll
            for (int r = 0; r < 4; ++r)
                Lpart[(size_t)jc * NROWS + wra + ti * 16 + g * 4 + r] = lr[ti][r];
        }
    }
}

// ---- merge: out[row][d] = sum_jc Op / sum_jc L ----
__global__ __launch_bounds__(256) void merge11(const float* __restrict__ Opart,
                                               const float* __restrict__ Lpart,
                                               float* __restrict__ out) {
    int gid = blockIdx.x * 256 + threadIdx.x;
    int row = gid >> 5;
    int dq  = (gid & 31) * 4;
    float4 sum = {0.f, 0.f, 0.f, 0.f};
    float L = 0.f;
#pragma unroll
    for (int jc = 0; jc < JSPLIT; ++jc) {
        float4 v = *(const float4*)(Opart + ((size_t)jc * NROWS + row) * DIM + dq);
        sum.x += v.x; sum.y += v.y; sum.z += v.z; sum.w += v.w;
        L += Lpart[(size_t)jc * NROWS + row];
    }
    float inv = 1.0f / fmaxf(L, 1e-37f);
    float4 ov = {sum.x * inv, sum.y * inv, sum.z * inv, sum.w * inv};
    *(float4*)(out + (size_t)row * DIM + dq) = ov;
}

extern "C" void kernel_launch(void* const* d_in, const int* in_sizes, int n_in,
                              void* d_out, int out_size, void* d_ws, size_t ws_size,
                              hipStream_t stream) {
    const float* xi   = (const float*)d_in[0];
    const float* xj   = (const float*)d_in[1];
    const int*   adj  = (const int*)d_in[2];
    const float* beta = (const float*)d_in[3];
    float* out = (float*)d_out;

    char* ws = (char*)d_ws;
    __hip_bfloat16* Qbf = (__hip_bfloat16*)ws;                                    // 2 MiB
    __hip_bfloat16* Kbf = (__hip_bfloat16*)(ws + (size_t)NROWS * DIM * 2);        // 2 MiB
    __hip_bfloat16* Vt  = (__hip_bfloat16*)(ws + 2 * (size_t)NROWS * DIM * 2);    // 2 MiB
    float*          Op  = (float*)(ws + 3 * (size_t)NROWS * DIM * 2);             // 32 MiB
    float*          Lp  = (float*)((char*)Op + (size_t)JSPLIT * NROWS * DIM * 4); // 256 KiB

    hipLaunchKernelGGL(prep11, dim3(2048), dim3(256), 0, stream, xi, xj, beta, Qbf, Kbf, Vt);
    hipLaunchKernelGGL(flash11, dim3(64 * JSPLIT), dim3(256), 0, stream, Qbf, Kbf, Vt, adj, Op, Lp);
    hipLaunchKernelGGL(merge11, dim3(1024), dim3(256), 0, stream, Op, Lp, out);
}